// Round 1
// baseline (234.590 us; speedup 1.0000x reference)
//
#include <hip/hip_runtime.h>

// HyperedgeAggregator: out[s, :] = mean over members i with segment_ids[i]==s
// of node_embeddings[node_indices[i], :].
//
// NUM_NODES=100000, EMBED_DIM=256, NUM_EDGES=16384, TOTAL=524288.
// segment_ids is SORTED -> binary search for segment extents, one wave per
// segment, no atomics. Each lane holds one float4 (4 dims) of the 256-dim
// accumulator; row loads are 64 lanes x 16B = 1 KiB coalesced.

#define EMBED_DIM 256
#define NUM_EDGES 16384
#define TOTAL_MEM 524288

__global__ __launch_bounds__(256) void hyperedge_agg_kernel(
    const float* __restrict__ emb,        // [NUM_NODES, EMBED_DIM]
    const int*   __restrict__ node_idx,   // [TOTAL_MEM]
    const int*   __restrict__ seg_ids,    // [TOTAL_MEM], sorted ascending
    float*       __restrict__ out)        // [NUM_EDGES, EMBED_DIM]
{
    const int wave = threadIdx.x >> 6;           // 4 waves per block
    const int lane = threadIdx.x & 63;
    const int seg  = blockIdx.x * 4 + wave;
    if (seg >= NUM_EDGES) return;

    // lower_bound(seg): first i with seg_ids[i] >= seg
    int lo = 0, hi = TOTAL_MEM;
    while (lo < hi) {
        int mid = (lo + hi) >> 1;
        if (seg_ids[mid] < seg) lo = mid + 1; else hi = mid;
    }
    const int start = lo;
    // lower_bound(seg+1), continuing from start
    hi = TOTAL_MEM;
    while (lo < hi) {
        int mid = (lo + hi) >> 1;
        if (seg_ids[mid] < seg + 1) lo = mid + 1; else hi = mid;
    }
    const int end = lo;

    float4 acc = make_float4(0.f, 0.f, 0.f, 0.f);
    for (int i = start; i < end; ++i) {
        const int n = node_idx[i];
        const float4* row = (const float4*)(emb + (long long)n * EMBED_DIM);
        float4 v = row[lane];
        acc.x += v.x; acc.y += v.y; acc.z += v.z; acc.w += v.w;
    }

    const float cnt = (end > start) ? (float)(end - start) : 1.0f;
    // true division to match reference seg_sum / counts exactly (to 1 ulp)
    acc.x /= cnt; acc.y /= cnt; acc.z /= cnt; acc.w /= cnt;

    ((float4*)(out + (long long)seg * EMBED_DIM))[lane] = acc;
}

extern "C" void kernel_launch(void* const* d_in, const int* in_sizes, int n_in,
                              void* d_out, int out_size, void* d_ws, size_t ws_size,
                              hipStream_t stream) {
    const float* emb      = (const float*)d_in[0];
    const int*   node_idx = (const int*)d_in[1];
    const int*   seg_ids  = (const int*)d_in[2];
    float*       out      = (float*)d_out;

    const int blocks = NUM_EDGES / 4;  // 4 segments (waves) per 256-thread block
    hyperedge_agg_kernel<<<blocks, 256, 0, stream>>>(emb, node_idx, seg_ids, out);
}

// Round 2
// 205.245 us; speedup vs baseline: 1.1430x; 1.1430x over previous
//
#include <hip/hip_runtime.h>

// HyperedgeAggregator: out[s, :] = mean over members i with segment_ids[i]==s
// of node_embeddings[node_indices[i], :].
//
// NUM_NODES=100000, EMBED_DIM=256, NUM_EDGES=16384, TOTAL=524288.
// segment_ids is SORTED. Two-kernel plan:
//   1) seg_bounds_kernel: one pass over seg_ids -> seg_start[NUM_EDGES+1] in d_ws
//   2) hyperedge_agg_kernel: one wave per segment; batch-load 64 member indices
//      (coalesced), broadcast via __shfl, keep 8 independent 1-KiB row gathers
//      in flight to cover HBM/L3 latency.

#define EMBED_DIM 256
#define NUM_EDGES 16384
#define TOTAL_MEM 524288

__global__ __launch_bounds__(256) void seg_bounds_kernel(
    const int* __restrict__ seg_ids,   // [TOTAL_MEM], sorted ascending
    int*       __restrict__ seg_start) // [NUM_EDGES+1]
{
    const int i = blockIdx.x * blockDim.x + threadIdx.x;
    if (i >= TOTAL_MEM) return;
    const int cur  = seg_ids[i];
    const int prev = (i == 0) ? -1 : seg_ids[i - 1];
    // thread i owns boundaries (prev, cur]
    for (int s = prev + 1; s <= cur; ++s) seg_start[s] = i;
    if (i == TOTAL_MEM - 1) {
        for (int s = cur + 1; s <= NUM_EDGES; ++s) seg_start[s] = TOTAL_MEM;
    }
}

__global__ __launch_bounds__(256) void hyperedge_agg_kernel(
    const float* __restrict__ emb,        // [NUM_NODES, EMBED_DIM]
    const int*   __restrict__ node_idx,   // [TOTAL_MEM]
    const int*   __restrict__ seg_start,  // [NUM_EDGES+1]
    float*       __restrict__ out)        // [NUM_EDGES, EMBED_DIM]
{
    const int wave = threadIdx.x >> 6;           // 4 waves per block
    const int lane = threadIdx.x & 63;
    const int seg  = blockIdx.x * 4 + wave;
    if (seg >= NUM_EDGES) return;

    const int start = seg_start[seg];
    const int end   = seg_start[seg + 1];

    float4 acc = make_float4(0.f, 0.f, 0.f, 0.f);

    int i = start;
    while (i < end) {
        const int batch = min(end - i, 64);
        // coalesced batch load of member indices; one per lane
        const int my = (lane < batch) ? node_idx[i + lane] : 0;

        for (int j = 0; j < batch; j += 8) {
            const int m = min(batch - j, 8);   // wave-uniform
            int ns[8];
            #pragma unroll
            for (int t = 0; t < 8; ++t) ns[t] = __shfl(my, j + t);
            float4 v[8];
            #pragma unroll
            for (int t = 0; t < 8; ++t)
                if (t < m)
                    v[t] = ((const float4*)(emb + (size_t)ns[t] * EMBED_DIM))[lane];
            #pragma unroll
            for (int t = 0; t < 8; ++t)
                if (t < m) {
                    acc.x += v[t].x; acc.y += v[t].y;
                    acc.z += v[t].z; acc.w += v[t].w;
                }
        }
        i += batch;
    }

    const float cnt = (end > start) ? (float)(end - start) : 1.0f;
    acc.x /= cnt; acc.y /= cnt; acc.z /= cnt; acc.w /= cnt;

    ((float4*)(out + (size_t)seg * EMBED_DIM))[lane] = acc;
}

// Fallback (no workspace): per-wave binary search, round-1 kernel.
__global__ __launch_bounds__(256) void hyperedge_agg_bsearch_kernel(
    const float* __restrict__ emb,
    const int*   __restrict__ node_idx,
    const int*   __restrict__ seg_ids,
    float*       __restrict__ out)
{
    const int wave = threadIdx.x >> 6;
    const int lane = threadIdx.x & 63;
    const int seg  = blockIdx.x * 4 + wave;
    if (seg >= NUM_EDGES) return;

    int lo = 0, hi = TOTAL_MEM;
    while (lo < hi) {
        int mid = (lo + hi) >> 1;
        if (seg_ids[mid] < seg) lo = mid + 1; else hi = mid;
    }
    const int start = lo;
    hi = TOTAL_MEM;
    while (lo < hi) {
        int mid = (lo + hi) >> 1;
        if (seg_ids[mid] < seg + 1) lo = mid + 1; else hi = mid;
    }
    const int end = lo;

    float4 acc = make_float4(0.f, 0.f, 0.f, 0.f);
    for (int i = start; i < end; ++i) {
        const int n = node_idx[i];
        float4 v = ((const float4*)(emb + (size_t)n * EMBED_DIM))[lane];
        acc.x += v.x; acc.y += v.y; acc.z += v.z; acc.w += v.w;
    }
    const float cnt = (end > start) ? (float)(end - start) : 1.0f;
    acc.x /= cnt; acc.y /= cnt; acc.z /= cnt; acc.w /= cnt;
    ((float4*)(out + (size_t)seg * EMBED_DIM))[lane] = acc;
}

extern "C" void kernel_launch(void* const* d_in, const int* in_sizes, int n_in,
                              void* d_out, int out_size, void* d_ws, size_t ws_size,
                              hipStream_t stream) {
    const float* emb      = (const float*)d_in[0];
    const int*   node_idx = (const int*)d_in[1];
    const int*   seg_ids  = (const int*)d_in[2];
    float*       out      = (float*)d_out;

    const size_t bounds_bytes = (size_t)(NUM_EDGES + 1) * sizeof(int);
    if (ws_size >= bounds_bytes) {
        int* seg_start = (int*)d_ws;
        seg_bounds_kernel<<<(TOTAL_MEM + 255) / 256, 256, 0, stream>>>(seg_ids, seg_start);
        hyperedge_agg_kernel<<<NUM_EDGES / 4, 256, 0, stream>>>(emb, node_idx, seg_start, out);
    } else {
        hyperedge_agg_bsearch_kernel<<<NUM_EDGES / 4, 256, 0, stream>>>(emb, node_idx, seg_ids, out);
    }
}

// Round 3
// 205.053 us; speedup vs baseline: 1.1440x; 1.0009x over previous
//
#include <hip/hip_runtime.h>

// HyperedgeAggregator: out[s, :] = mean over members i with segment_ids[i]==s
// of node_embeddings[node_indices[i], :].
//
// NUM_NODES=100000, EMBED_DIM=256, NUM_EDGES=16384, TOTAL=524288.
// segment_ids is SORTED. Two-kernel plan:
//   1) seg_bounds_kernel: one pass over seg_ids -> seg_start[NUM_EDGES+1] in d_ws
//   2) hyperedge_agg_kernel: one wave per segment. Member indices batch-loaded
//      (coalesced) and broadcast via __shfl. Row gathers are SOFTWARE-PIPELINED
//      in groups of 8: group g+1's loads issue before group g is consumed, so
//      each wave keeps 16 x 1KiB loads in flight (waits are vmcnt(8), not 0).

#define EMBED_DIM 256
#define NUM_EDGES 16384
#define TOTAL_MEM 524288

__global__ __launch_bounds__(256) void seg_bounds_kernel(
    const int* __restrict__ seg_ids,   // [TOTAL_MEM], sorted ascending
    int*       __restrict__ seg_start) // [NUM_EDGES+1]
{
    const int i = blockIdx.x * blockDim.x + threadIdx.x;
    if (i >= TOTAL_MEM) return;
    const int cur  = seg_ids[i];
    const int prev = (i == 0) ? -1 : seg_ids[i - 1];
    for (int s = prev + 1; s <= cur; ++s) seg_start[s] = i;
    if (i == TOTAL_MEM - 1) {
        for (int s = cur + 1; s <= NUM_EDGES; ++s) seg_start[s] = TOTAL_MEM;
    }
}

__global__ __launch_bounds__(256) void hyperedge_agg_kernel(
    const float* __restrict__ emb,        // [NUM_NODES, EMBED_DIM]
    const int*   __restrict__ node_idx,   // [TOTAL_MEM]
    const int*   __restrict__ seg_start,  // [NUM_EDGES+1]
    float*       __restrict__ out)        // [NUM_EDGES, EMBED_DIM]
{
    const int wave = threadIdx.x >> 6;           // 4 waves per block
    const int lane = threadIdx.x & 63;
    const int seg  = blockIdx.x * 4 + wave;
    if (seg >= NUM_EDGES) return;

    const int start = seg_start[seg];
    const int end   = seg_start[seg + 1];

    float4 acc = make_float4(0.f, 0.f, 0.f, 0.f);

    int i = start;
    while (i < end) {
        const int batch = min(end - i, 64);
        // coalesced batch load of member indices; one per lane
        const int my = (lane < batch) ? node_idx[i + lane] : 0;
        const int nGroups = (batch + 7) >> 3;

        float4 v0[8], v1[8];

        // prologue: issue group 0's loads
        int m0 = min(batch, 8);
        #pragma unroll
        for (int t = 0; t < 8; ++t)
            if (t < m0) {
                const int n = __shfl(my, t);
                v0[t] = ((const float4*)(emb + (size_t)n * EMBED_DIM))[lane];
            }

        for (int g = 1; g < nGroups; ++g) {
            const int j  = g << 3;
            const int m1 = min(batch - j, 8);
            // issue group g's loads BEFORE consuming group g-1
            #pragma unroll
            for (int t = 0; t < 8; ++t)
                if (t < m1) {
                    const int n = __shfl(my, j + t);
                    v1[t] = ((const float4*)(emb + (size_t)n * EMBED_DIM))[lane];
                }
            // consume group g-1 (always a full 8: only the last group is partial)
            #pragma unroll
            for (int t = 0; t < 8; ++t) {
                acc.x += v0[t].x; acc.y += v0[t].y;
                acc.z += v0[t].z; acc.w += v0[t].w;
            }
            #pragma unroll
            for (int t = 0; t < 8; ++t) v0[t] = v1[t];
            m0 = m1;
        }

        // epilogue: consume the final group
        #pragma unroll
        for (int t = 0; t < 8; ++t)
            if (t < m0) {
                acc.x += v0[t].x; acc.y += v0[t].y;
                acc.z += v0[t].z; acc.w += v0[t].w;
            }

        i += batch;
    }

    const float cnt = (end > start) ? (float)(end - start) : 1.0f;
    acc.x /= cnt; acc.y /= cnt; acc.z /= cnt; acc.w /= cnt;

    ((float4*)(out + (size_t)seg * EMBED_DIM))[lane] = acc;
}

// Fallback (no workspace): per-wave binary search.
__global__ __launch_bounds__(256) void hyperedge_agg_bsearch_kernel(
    const float* __restrict__ emb,
    const int*   __restrict__ node_idx,
    const int*   __restrict__ seg_ids,
    float*       __restrict__ out)
{
    const int wave = threadIdx.x >> 6;
    const int lane = threadIdx.x & 63;
    const int seg  = blockIdx.x * 4 + wave;
    if (seg >= NUM_EDGES) return;

    int lo = 0, hi = TOTAL_MEM;
    while (lo < hi) {
        int mid = (lo + hi) >> 1;
        if (seg_ids[mid] < seg) lo = mid + 1; else hi = mid;
    }
    const int start = lo;
    hi = TOTAL_MEM;
    while (lo < hi) {
        int mid = (lo + hi) >> 1;
        if (seg_ids[mid] < seg + 1) lo = mid + 1; else hi = mid;
    }
    const int end = lo;

    float4 acc = make_float4(0.f, 0.f, 0.f, 0.f);
    for (int i = start; i < end; ++i) {
        const int n = node_idx[i];
        float4 v = ((const float4*)(emb + (size_t)n * EMBED_DIM))[lane];
        acc.x += v.x; acc.y += v.y; acc.z += v.z; acc.w += v.w;
    }
    const float cnt = (end > start) ? (float)(end - start) : 1.0f;
    acc.x /= cnt; acc.y /= cnt; acc.z /= cnt; acc.w /= cnt;
    ((float4*)(out + (size_t)seg * EMBED_DIM))[lane] = acc;
}

extern "C" void kernel_launch(void* const* d_in, const int* in_sizes, int n_in,
                              void* d_out, int out_size, void* d_ws, size_t ws_size,
                              hipStream_t stream) {
    const float* emb      = (const float*)d_in[0];
    const int*   node_idx = (const int*)d_in[1];
    const int*   seg_ids  = (const int*)d_in[2];
    float*       out      = (float*)d_out;

    const size_t bounds_bytes = (size_t)(NUM_EDGES + 1) * sizeof(int);
    if (ws_size >= bounds_bytes) {
        int* seg_start = (int*)d_ws;
        seg_bounds_kernel<<<(TOTAL_MEM + 255) / 256, 256, 0, stream>>>(seg_ids, seg_start);
        hyperedge_agg_kernel<<<NUM_EDGES / 4, 256, 0, stream>>>(emb, node_idx, seg_start, out);
    } else {
        hyperedge_agg_bsearch_kernel<<<NUM_EDGES / 4, 256, 0, stream>>>(emb, node_idx, seg_ids, out);
    }
}